// Round 2
// baseline (5223.032 us; speedup 1.0000x reference)
//
#include <hip/hip_runtime.h>
#include <hip/hip_bf16.h>
#include <math.h>

// Problem constants
constexpr int B = 128;
constexpr int T = 256;
constexpr int H = 200;       // hidden
constexpr int G4 = 800;      // 4*H
constexpr int BT = B * T;    // 32768
constexpr int K0 = 360, K0P = 384;   // layer0 input dim, padded to %32
constexpr int K1 = 400, K1P = 416;   // layer1 input dim, padded to %32

typedef __bf16 bf16x8 __attribute__((ext_vector_type(8)));
typedef float f32x4 __attribute__((ext_vector_type(4)));
typedef unsigned short ushortx4 __attribute__((ext_vector_type(4)));

__device__ __forceinline__ float bfr2f(unsigned short u) {
  union { unsigned int i; float f; } x;
  x.i = ((unsigned int)u) << 16;
  return x.f;
}

// ---------------------------------------------------------------------------
// Dtype detector: if the "float" inputs are actually f32 storage, reading the
// raw ushorts shows ~25% of low-half words with exponent >= 0xC0 (|x| >= 2^65),
// impossible for N(0,0.08) bf16 data. flag=1 -> f32 storage, flag=0 -> bf16.
__global__ void detect_dtype(const unsigned short* __restrict__ raw,
                             int* __restrict__ flag) {
  __shared__ int cnt[256];
  int c = 0;
  for (int j = 0; j < 32; ++j) {
    unsigned short u = raw[1024 + threadIdx.x * 32 + j];
    int e = (u >> 7) & 0xFF;
    if (e >= 0xC0) ++c;
  }
  cnt[threadIdx.x] = c;
  __syncthreads();
  for (int off = 128; off > 0; off >>= 1) {
    if (threadIdx.x < off) cnt[threadIdx.x] += cnt[threadIdx.x + off];
    __syncthreads();
  }
  if (threadIdx.x == 0) *flag = (cnt[0] > 16) ? 1 : 0;
}

// Generic convert-to-bf16 (f32 world) or raw copy (bf16 world)
__global__ void conv_to_bf16(const void* __restrict__ src,
                             __hip_bfloat16* __restrict__ dst, int n,
                             const int* __restrict__ flag) {
  int f = *flag;
  int stride = gridDim.x * blockDim.x;
  for (int i = blockIdx.x * blockDim.x + threadIdx.x; i < n; i += stride) {
    if (f) dst[i] = __float2bfloat16(((const float*)src)[i]);
    else   ((unsigned short*)dst)[i] = ((const unsigned short*)src)[i];
  }
}

// ---------------------------------------------------------------------------
// Embedding concat: X0[bt][0:300]=embC[words], [300:330]=posC, [330:360]=nerC,
// [360:384]=0 (K-pad for MFMA). Tables already converted to bf16.
__global__ void embed_kernel(const int* __restrict__ words,
                             const int* __restrict__ pos,
                             const int* __restrict__ ner,
                             const __hip_bfloat16* __restrict__ embC,
                             const __hip_bfloat16* __restrict__ posC,
                             const __hip_bfloat16* __restrict__ nerC,
                             __hip_bfloat16* __restrict__ X0) {
  int bt = blockIdx.x;
  int w = words[bt], p = pos[bt], nr = ner[bt];
  for (int j = threadIdx.x; j < K0P; j += blockDim.x) {
    __hip_bfloat16 v;
    if (j < 300)       v = embC[(size_t)w * 300 + j];
    else if (j < 330)  v = posC[(size_t)p * 30 + (j - 300)];
    else if (j < 360)  v = nerC[(size_t)nr * 30 + (j - 330)];
    else               v = __float2bfloat16(0.0f);
    X0[(size_t)bt * K0P + j] = v;
  }
}

// Zero the K-pad tail columns [400:416) of X1
__global__ void zero_x1_tail(__hip_bfloat16* __restrict__ X1) {
  int idx = blockIdx.x * blockDim.x + threadIdx.x;  // BT*16 threads
  int bt = idx >> 4, j = idx & 15;
  X1[(size_t)bt * K1P + 400 + j] = __float2bfloat16(0.0f);
}

// Pad-copy a weight matrix [rows,K] -> [rows,Kp] with zero fill (+dtype conv)
__global__ void pad_copy(const void* __restrict__ src,
                         __hip_bfloat16* __restrict__ dst, int K, int Kp,
                         const int* __restrict__ flag) {
  int r = blockIdx.x;
  int f = *flag;
  for (int j = threadIdx.x; j < Kp; j += blockDim.x) {
    __hip_bfloat16 v = __float2bfloat16(0.0f);
    if (j < K)
      v = f ? __float2bfloat16(((const float*)src)[(size_t)r * K + j])
            : ((const __hip_bfloat16*)src)[(size_t)r * K + j];
    dst[(size_t)r * Kp + j] = v;
  }
}

// Transpose W_hh [800,200] -> whhT [200,800] (+dtype conv)
__global__ void transpose_whh(const void* __restrict__ src,
                              __hip_bfloat16* __restrict__ dst,
                              const int* __restrict__ flag) {
  int idx = blockIdx.x * blockDim.x + threadIdx.x;
  int f = *flag;
  if (idx < G4 * H) {
    int n = idx / H, k = idx % H;
    __hip_bfloat16 v = f ? __float2bfloat16(((const float*)src)[idx])
                         : ((const __hip_bfloat16*)src)[idx];
    dst[(size_t)k * G4 + n] = v;
  }
}

// ---------------------------------------------------------------------------
// MFMA GEMM: C[M,800] = A[M,Kp] @ Bm[800,Kp]^T   (bf16 in, fp32 acc, bf16 out)
// grid (M/64, ceil(800/64)=13), block 256 (4 waves, 2x2 of 16x16 frags each)
__global__ __launch_bounds__(256) void gemm_bt(
    const __hip_bfloat16* __restrict__ A,
    const __hip_bfloat16* __restrict__ Bm,
    __hip_bfloat16* __restrict__ C,
    int N, int Kp) {
  const int lane = threadIdx.x & 63;
  const int wave = threadIdx.x >> 6;
  const int l15 = lane & 15, quad = lane >> 4;
  const int m0 = blockIdx.x * 64 + (wave & 1) * 32;
  const int n0 = blockIdx.y * 64 + (wave >> 1) * 32;

  f32x4 acc[2][2] = {};

  int c0 = n0 + l15;       if (c0 > N - 1) c0 = N - 1;
  int c1 = n0 + 16 + l15;  if (c1 > N - 1) c1 = N - 1;
  const size_t ar0 = (size_t)(m0 + l15) * Kp;
  const size_t ar1 = (size_t)(m0 + 16 + l15) * Kp;
  const size_t br0 = (size_t)c0 * Kp;
  const size_t br1 = (size_t)c1 * Kp;

  for (int k0 = 0; k0 < Kp; k0 += 32) {
    int ko = k0 + quad * 8;
    bf16x8 a0 = *(const bf16x8*)(A + ar0 + ko);
    bf16x8 a1 = *(const bf16x8*)(A + ar1 + ko);
    bf16x8 b0 = *(const bf16x8*)(Bm + br0 + ko);
    bf16x8 b1 = *(const bf16x8*)(Bm + br1 + ko);
    acc[0][0] = __builtin_amdgcn_mfma_f32_16x16x32_bf16(a0, b0, acc[0][0], 0, 0, 0);
    acc[0][1] = __builtin_amdgcn_mfma_f32_16x16x32_bf16(a0, b1, acc[0][1], 0, 0, 0);
    acc[1][0] = __builtin_amdgcn_mfma_f32_16x16x32_bf16(a1, b0, acc[1][0], 0, 0, 0);
    acc[1][1] = __builtin_amdgcn_mfma_f32_16x16x32_bf16(a1, b1, acc[1][1], 0, 0, 0);
  }
  // C/D layout: col = lane&15, row = quad*4 + r   [verified m89/m91]
  #pragma unroll
  for (int mi = 0; mi < 2; ++mi)
    #pragma unroll
    for (int ni = 0; ni < 2; ++ni)
      #pragma unroll
      for (int r = 0; r < 4; ++r) {
        int row = m0 + mi * 16 + quad * 4 + r;
        int col = n0 + ni * 16 + l15;
        if (col < N)
          C[(size_t)row * N + col] = __float2bfloat16(acc[mi][ni][r]);
      }
}

// ---------------------------------------------------------------------------
// One bidirectional LSTM layer (both dirs in grid). grid=128 (dir=blk&1,
// 2 batch rows per wg), block=256. Gpre holds x@W_ih^T (no bias) per dir.
__global__ __launch_bounds__(256) void lstm_layer(
    const __hip_bfloat16* __restrict__ Gpre,   // [2][B][T][800]
    const __hip_bfloat16* __restrict__ whhT,   // [2][200][800]
    const __hip_bfloat16* __restrict__ bias_f, // [800]
    const __hip_bfloat16* __restrict__ bias_b, // [800]
    const int* __restrict__ masks,             // [B][T], 1 = pad
    __hip_bfloat16* __restrict__ out,          // [B][T][ostride], cols dir*200..+200
    int ostride,
    float* __restrict__ final_h)               // [B][400] = [hb | hf], or nullptr
{
  const int tid = threadIdx.x;
  const int dir = blockIdx.x & 1;
  const int b0  = (blockIdx.x >> 1) * 2;

  __shared__ float hsh[2][H];
  __shared__ float csh[2][H];
  __shared__ float gsh[2][G4];

  for (int i = tid; i < 2 * H; i += 256) {
    ((float*)hsh)[i] = 0.0f;
    ((float*)csh)[i] = 0.0f;
  }
  __syncthreads();

  const __hip_bfloat16* bias = dir ? bias_b : bias_f;
  const unsigned short* wp_base = (const unsigned short*)whhT + (size_t)dir * H * G4;
  const unsigned short* gp_base = (const unsigned short*)Gpre + (size_t)dir * BT * G4;
  const int cbase = dir * H;
  const int n4 = tid * 4;
  const unsigned short* wp = wp_base + n4;

  float bs[4] = {0.f, 0.f, 0.f, 0.f};
  if (tid < H) {
    #pragma unroll
    for (int i = 0; i < 4; ++i) bs[i] = __bfloat162float(bias[n4 + i]);
  }

  for (int tt = 0; tt < T; ++tt) {
    const int t = dir ? (T - 1 - tt) : tt;
    if (tid < H) {
      float a0[4], a1[4];
      ushortx4 g0 = *(const ushortx4*)(gp_base + ((size_t)b0 * T + t) * G4 + n4);
      ushortx4 g1 = *(const ushortx4*)(gp_base + ((size_t)(b0 + 1) * T + t) * G4 + n4);
      #pragma unroll
      for (int i = 0; i < 4; ++i) {
        a0[i] = bfr2f(g0[i]) + bs[i];
        a1[i] = bfr2f(g1[i]) + bs[i];
      }
      for (int k = 0; k < H; k += 8) {
        ushortx4 wv[8];
        #pragma unroll
        for (int u = 0; u < 8; ++u)
          wv[u] = *(const ushortx4*)(wp + (size_t)(k + u) * G4);
        #pragma unroll
        for (int u = 0; u < 8; ++u) {
          float h0v = hsh[0][k + u], h1v = hsh[1][k + u];
          #pragma unroll
          for (int i = 0; i < 4; ++i) {
            float wf = bfr2f(wv[u][i]);
            a0[i] += h0v * wf;
            a1[i] += h1v * wf;
          }
        }
      }
      #pragma unroll
      for (int i = 0; i < 4; ++i) {
        gsh[0][n4 + i] = a0[i];
        gsh[1][n4 + i] = a1[i];
      }
    }
    __syncthreads();
    if (tid < H) {
      #pragma unroll
      for (int r = 0; r < 2; ++r) {
        float gi = gsh[r][tid];
        float gf = gsh[r][H + tid];
        float gc = gsh[r][2 * H + tid];
        float go = gsh[r][3 * H + tid];
        float si = 1.0f / (1.0f + expf(-gi));
        float sf = 1.0f / (1.0f + expf(-gf));
        float so = 1.0f / (1.0f + expf(-go));
        float cn = sf * csh[r][tid] + si * tanhf(gc);
        float hn = so * tanhf(cn);
        bool kp = (masks[(b0 + r) * T + t] == 0);
        hsh[r][tid] = kp ? hn : hsh[r][tid];
        csh[r][tid] = kp ? cn : csh[r][tid];
        out[((size_t)(b0 + r) * T + t) * ostride + cbase + tid] =
            __float2bfloat16(kp ? hn : 0.0f);
      }
    }
    __syncthreads();
  }
  if (final_h != nullptr && tid < H) {
    // glob_h = [hb1 | hf1]: backward -> cols 0..199, forward -> cols 200..399
    int col = dir ? tid : (H + tid);
    final_h[(size_t)b0 * 400 + col]       = hsh[0][tid];
    final_h[(size_t)(b0 + 1) * 400 + col] = hsh[1][tid];
  }
}

// ---------------------------------------------------------------------------
// Span sums: subj_h/obj_h[b][d] = sum_t rnn[b][t][d] * ((sel_pos+mask)==0)
__global__ __launch_bounds__(256) void span_sum(
    const __hip_bfloat16* __restrict__ rnn,   // [B][T][400]
    const int* __restrict__ masks,
    const int* __restrict__ subj_pos,
    const int* __restrict__ obj_pos,
    float* __restrict__ obj_h,   // [B][400]
    float* __restrict__ subj_h)  // [B][400]
{
  int b = blockIdx.x;
  for (int d = threadIdx.x; d < 400; d += 256) {
    float ss = 0.f, so = 0.f;
    for (int t = 0; t < T; ++t) {
      int m = masks[b * T + t];
      float v = __bfloat162float(rnn[((size_t)b * T + t) * 400 + d]);
      if (subj_pos[b * T + t] + m == 0) ss += v;
      if (obj_pos[b * T + t] + m == 0) so += v;
    }
    subj_h[(size_t)b * 400 + d] = ss;
    obj_h[(size_t)b * 400 + d] = so;
  }
}

// ---------------------------------------------------------------------------
// Single-query attention pooling. grid = 3*128 (qi = blk>>7, b = blk&127)
__global__ __launch_bounds__(256) void attn_pool_k(
    const float* __restrict__ qbuf,           // [3][B][400]
    const __hip_bfloat16* __restrict__ rnn,   // [B][T][400]
    const int* __restrict__ masks,
    float* __restrict__ outp)                 // [3][B][400]
{
  int b = blockIdx.x & 127;
  int qi = blockIdx.x >> 7;
  __shared__ float qs[400];
  __shared__ float ps[256];
  __shared__ float red[256];
  const float* q = qbuf + ((size_t)qi * B + b) * 400;
  for (int d = threadIdx.x; d < 400; d += 256) qs[d] = q[d];
  __syncthreads();

  int t = threadIdx.x;
  const __hip_bfloat16* kv = rnn + ((size_t)b * T + t) * 400;
  float s = 0.f;
  for (int d = 0; d < 400; ++d) s += qs[d] * __bfloat162float(kv[d]);
  s *= 0.05f;  // 1/sqrt(400)
  if (masks[b * T + t] != 0) s = -1e9f;

  red[t] = s;
  __syncthreads();
  for (int off = 128; off > 0; off >>= 1) {
    if (t < off) red[t] = fmaxf(red[t], red[t + off]);
    __syncthreads();
  }
  float mx = red[0];
  __syncthreads();
  float e = expf(s - mx);
  red[t] = e;
  __syncthreads();
  for (int off = 128; off > 0; off >>= 1) {
    if (t < off) red[t] += red[t + off];
    __syncthreads();
  }
  float inv = 1.0f / red[0];
  ps[t] = e * inv;
  __syncthreads();

  for (int d = threadIdx.x; d < 400; d += 256) {
    float acc = 0.f;
    for (int t2 = 0; t2 < T; ++t2)
      acc += ps[t2] * __bfloat162float(rnn[((size_t)b * T + t2) * 400 + d]);
    outp[((size_t)qi * B + b) * 400 + d] = acc;
  }
}

// ---------------------------------------------------------------------------
// Head: h = relu(obj_a@wo^T+wo_b + subj_a@ws^T+ws_b + glob_a@wg^T+wg_b);
// logits = h@cls^T + cls_b. grid = 128, block = 256. Writes bf16 or f32 per flag.
__global__ __launch_bounds__(256) void final_head(
    const float* __restrict__ attn,   // [3][B][400]: 0=obj,1=subj,2=glob
    const __hip_bfloat16* __restrict__ wo_w, const __hip_bfloat16* __restrict__ wo_b,
    const __hip_bfloat16* __restrict__ ws_w, const __hip_bfloat16* __restrict__ ws_b,
    const __hip_bfloat16* __restrict__ wg_w, const __hip_bfloat16* __restrict__ wg_b,
    const __hip_bfloat16* __restrict__ cls_w, const __hip_bfloat16* __restrict__ cls_b,
    void* __restrict__ outp,          // [B][2]
    const int* __restrict__ flag)
{
  int b = blockIdx.x;
  __shared__ float hs[H];
  int j = threadIdx.x;
  if (j < H) {
    float acc = __bfloat162float(wo_b[j]) + __bfloat162float(ws_b[j]) +
                __bfloat162float(wg_b[j]);
    const float* oa = attn + ((size_t)0 * B + b) * 400;
    const float* sa = attn + ((size_t)1 * B + b) * 400;
    const float* ga = attn + ((size_t)2 * B + b) * 400;
    for (int d = 0; d < 400; ++d) {
      acc += oa[d] * __bfloat162float(wo_w[(size_t)j * 400 + d]);
      acc += sa[d] * __bfloat162float(ws_w[(size_t)j * 400 + d]);
      acc += ga[d] * __bfloat162float(wg_w[(size_t)j * 400 + d]);
    }
    hs[j] = fmaxf(acc, 0.0f);
  }
  __syncthreads();
  if (j < 2) {
    float a = __bfloat162float(cls_b[j]);
    for (int k = 0; k < H; ++k)
      a += hs[k] * __bfloat162float(cls_w[(size_t)j * H + k]);
    if (*flag) ((float*)outp)[b * 2 + j] = a;
    else       ((__hip_bfloat16*)outp)[b * 2 + j] = __float2bfloat16(a);
  }
}

// ---------------------------------------------------------------------------
// Workspace layout (bytes, 16B-aligned)
constexpr size_t O_X0   = 0;            // 32768*384*2  = 25165824
constexpr size_t O_X1   = 25165824;     // 32768*416*2  = 27262976
constexpr size_t O_GPRE = 52428800;     // 2*32768*800*2 = 104857600 (embC overlaid pre-GEMM)
constexpr size_t O_RNN  = 157286400;    // 32768*400*2  = 26214400
constexpr size_t O_WIH0 = 183500800;    // 2*800*384*2  = 1228800
constexpr size_t O_WIH1 = 184729600;    // 2*800*416*2  = 1331200
constexpr size_t O_WHHT = 186060800;    // 4*200*800*2  = 1280000
constexpr size_t O_Q    = 187340800;    // 3*128*400*4  = 614400
constexpr size_t O_ATT  = 187955200;    // 614400
constexpr size_t O_FLAG = 188569600;    // 256
constexpr size_t O_POSC = 188569856;    // 1500*2 -> 3008
constexpr size_t O_NERC = 188572864;    // 750*2  -> 1504
constexpr size_t O_BIAS = 188574368;    // 4*800*2 = 6400
constexpr size_t O_WOW  = 188580768;    // 80000*2 = 160000
constexpr size_t O_WSW  = 188740768;
constexpr size_t O_WGW  = 188900768;
constexpr size_t O_WOB  = 189060768;    // 200*2 -> 400
constexpr size_t O_WSB  = 189061168;
constexpr size_t O_WGB  = 189061568;
constexpr size_t O_CLSW = 189061968;    // 400*2 = 800
constexpr size_t O_CLSB = 189062768;    // 2*2 -> 16

extern "C" void kernel_launch(void* const* d_in, const int* in_sizes, int n_in,
                              void* d_out, int out_size, void* d_ws, size_t ws_size,
                              hipStream_t stream) {
  (void)in_sizes; (void)n_in; (void)out_size; (void)ws_size;

  const int* words = (const int*)d_in[0];
  const int* masks = (const int*)d_in[1];
  const int* pos   = (const int*)d_in[2];
  const int* ner   = (const int*)d_in[3];
  const int* subj  = (const int*)d_in[4];
  const int* obj   = (const int*)d_in[5];
  const void* emb_w = d_in[6];
  const void* pos_w = d_in[7];
  const void* ner_w = d_in[8];
  const void* wih[4]  = {d_in[9],  d_in[12], d_in[15], d_in[18]};
  const void* whh[4]  = {d_in[10], d_in[13], d_in[16], d_in[19]};
  const void* bias[4] = {d_in[11], d_in[14], d_in[17], d_in[20]};
  const void* wo_w = d_in[21]; const void* wo_b = d_in[22];
  const void* ws_w = d_in[23]; const void* ws_b = d_in[24];
  const void* wg_w = d_in[25]; const void* wg_b = d_in[26];
  const void* cls_w = d_in[27]; const void* cls_b = d_in[28];

  char* ws = (char*)d_ws;
  __hip_bfloat16* X0   = (__hip_bfloat16*)(ws + O_X0);
  __hip_bfloat16* X1   = (__hip_bfloat16*)(ws + O_X1);
  __hip_bfloat16* Gpre = (__hip_bfloat16*)(ws + O_GPRE);
  __hip_bfloat16* embC = (__hip_bfloat16*)(ws + O_GPRE);  // overlaid (dead before GEMM)
  __hip_bfloat16* RNN  = (__hip_bfloat16*)(ws + O_RNN);
  __hip_bfloat16* wih0p = (__hip_bfloat16*)(ws + O_WIH0);  // [2][800][384]
  __hip_bfloat16* wih1p = (__hip_bfloat16*)(ws + O_WIH1);  // [2][800][416]
  __hip_bfloat16* whhT  = (__hip_bfloat16*)(ws + O_WHHT);  // [4][200][800]
  float* qbuf = (float*)(ws + O_Q);    // [3][B][400]: obj, subj, glob
  float* attb = (float*)(ws + O_ATT);  // [3][B][400]
  int* flag = (int*)(ws + O_FLAG);
  __hip_bfloat16* posC = (__hip_bfloat16*)(ws + O_POSC);
  __hip_bfloat16* nerC = (__hip_bfloat16*)(ws + O_NERC);
  __hip_bfloat16* biasC = (__hip_bfloat16*)(ws + O_BIAS);  // [4][800]
  __hip_bfloat16* woW = (__hip_bfloat16*)(ws + O_WOW);
  __hip_bfloat16* wsW = (__hip_bfloat16*)(ws + O_WSW);
  __hip_bfloat16* wgW = (__hip_bfloat16*)(ws + O_WGW);
  __hip_bfloat16* woB = (__hip_bfloat16*)(ws + O_WOB);
  __hip_bfloat16* wsB = (__hip_bfloat16*)(ws + O_WSB);
  __hip_bfloat16* wgB = (__hip_bfloat16*)(ws + O_WGB);
  __hip_bfloat16* clsW = (__hip_bfloat16*)(ws + O_CLSW);
  __hip_bfloat16* clsB = (__hip_bfloat16*)(ws + O_CLSB);

  // --- dtype detect + conversions ---
  detect_dtype<<<1, 256, 0, stream>>>((const unsigned short*)emb_w, flag);
  conv_to_bf16<<<1024, 256, 0, stream>>>(emb_w, embC, 40000 * 300, flag);
  conv_to_bf16<<<2, 256, 0, stream>>>(pos_w, posC, 50 * 30, flag);
  conv_to_bf16<<<1, 256, 0, stream>>>(ner_w, nerC, 25 * 30, flag);
  for (int i = 0; i < 4; ++i)
    conv_to_bf16<<<2, 256, 0, stream>>>(bias[i], biasC + i * G4, G4, flag);
  conv_to_bf16<<<64, 256, 0, stream>>>(wo_w, woW, H * 400, flag);
  conv_to_bf16<<<64, 256, 0, stream>>>(ws_w, wsW, H * 400, flag);
  conv_to_bf16<<<64, 256, 0, stream>>>(wg_w, wgW, H * 400, flag);
  conv_to_bf16<<<1, 256, 0, stream>>>(wo_b, woB, H, flag);
  conv_to_bf16<<<1, 256, 0, stream>>>(ws_b, wsB, H, flag);
  conv_to_bf16<<<1, 256, 0, stream>>>(wg_b, wgB, H, flag);
  conv_to_bf16<<<1, 256, 0, stream>>>(cls_w, clsW, 2 * H, flag);
  conv_to_bf16<<<1, 256, 0, stream>>>(cls_b, clsB, 2, flag);

  // --- weight prep ---
  pad_copy<<<G4, 128, 0, stream>>>(wih[0], wih0p,               K0, K0P, flag);
  pad_copy<<<G4, 128, 0, stream>>>(wih[1], wih0p + G4 * K0P,    K0, K0P, flag);
  pad_copy<<<G4, 128, 0, stream>>>(wih[2], wih1p,               K1, K1P, flag);
  pad_copy<<<G4, 128, 0, stream>>>(wih[3], wih1p + G4 * K1P,    K1, K1P, flag);
  for (int i = 0; i < 4; ++i)
    transpose_whh<<<625, 256, 0, stream>>>(whh[i], whhT + (size_t)i * H * G4, flag);

  // --- embedding + X1 pad ---
  embed_kernel<<<BT, 128, 0, stream>>>(words, pos, ner, embC, posC, nerC, X0);
  zero_x1_tail<<<2048, 256, 0, stream>>>(X1);

  dim3 ggrid(BT / 64, 13);

  // --- layer 0: input projections + recurrence ---
  gemm_bt<<<ggrid, 256, 0, stream>>>(X0, wih0p,            Gpre,                   G4, K0P);
  gemm_bt<<<ggrid, 256, 0, stream>>>(X0, wih0p + G4 * K0P, Gpre + (size_t)BT * G4, G4, K0P);
  lstm_layer<<<128, 256, 0, stream>>>(Gpre, whhT, biasC, biasC + G4, masks,
                                      X1, K1P, nullptr);

  // --- layer 1 ---
  gemm_bt<<<ggrid, 256, 0, stream>>>(X1, wih1p,            Gpre,                   G4, K1P);
  gemm_bt<<<ggrid, 256, 0, stream>>>(X1, wih1p + G4 * K1P, Gpre + (size_t)BT * G4, G4, K1P);
  float* qglob = qbuf + (size_t)2 * B * 400;
  lstm_layer<<<128, 256, 0, stream>>>(Gpre, whhT + (size_t)2 * H * G4,
                                      biasC + 2 * G4, biasC + 3 * G4, masks,
                                      RNN, 400, qglob);

  // --- span sums (obj -> slot0, subj -> slot1) ---
  span_sum<<<B, 256, 0, stream>>>(RNN, masks, subj, obj,
                                  qbuf, qbuf + (size_t)B * 400);

  // --- attention pooling (3 queries) ---
  attn_pool_k<<<3 * B, 256, 0, stream>>>(qbuf, RNN, masks, attb);

  // --- head ---
  final_head<<<B, 256, 0, stream>>>(attb, woW, woB, wsW, wsB, wgW, wgB,
                                    clsW, clsB, d_out, flag);
}